// Round 2
// baseline (855.819 us; speedup 1.0000x reference)
//
#include <hip/hip_runtime.h>
#include <hip/hip_fp16.h>
#include <math.h>

// Problem constants
#define S 2048
#define D 64
#define BH 32          // B*H
#define TILE 64
#define NT (S / TILE)  // 32
#define SP1 (S + 1)    // 2049
#define OS_PITCH 66    // fp32 pitch for store-transpose tile: 2-way max bank alias (free)

typedef _Float16 f16;
typedef f16 f16x8 __attribute__((ext_vector_type(8)));
typedef float f32x4 __attribute__((ext_vector_type(4)));

// ---------------------------------------------------------------------------
// prep: one wave per row (of BH*S). kh = f16(k * 1/||k||), qh = f16(q).
// Folding rinv into kh makes MFMA produce q·k_hat directly.
// ---------------------------------------------------------------------------
__global__ __launch_bounds__(256) void prep_kernel(const float* __restrict__ q,
                                                   const float* __restrict__ k,
                                                   f16* __restrict__ qh,
                                                   f16* __restrict__ kh) {
    int row  = (blockIdx.x * 256 + threadIdx.x) >> 6;
    int lane = threadIdx.x & 63;
    size_t idx = (size_t)row * D + lane;
    float kv = k[idx];
    float s = kv * kv;
    #pragma unroll
    for (int off = 32; off; off >>= 1) s += __shfl_xor(s, off);
    float rinv = rsqrtf(s);
    kh[idx] = (f16)(kv * rinv);
    qh[idx] = (f16)q[idx];
}

// ---------------------------------------------------------------------------
// main: block = (it, bh) owns output rows [i0, i0+64) x [0, 2049).
// No barriers: MFMA fragments loaded straight from global (L2-resident),
// LDS only used wave-locally to transpose MFMA-layout -> row-contiguous stores.
// MFMA 16x16x32 f16; C/D: col=lane&15, row=(lane>>4)*4+reg.
// ---------------------------------------------------------------------------
__global__ __launch_bounds__(256) void main_kernel(const f16* __restrict__ qh,
                                                   const f16* __restrict__ kh,
                                                   const float* __restrict__ sinks,
                                                   float* __restrict__ out) {
    __shared__ __align__(16) float os[TILE * OS_PITCH];  // wave w uses rows [w*16, w*16+16)

    const int it   = blockIdx.x;
    const int bh   = blockIdx.y;
    const int i0   = it * TILE;
    const int tid  = threadIdx.x;
    const int lane = tid & 63;
    const int w    = tid >> 6;
    const int m    = lane & 15;
    const int quad = lane >> 4;

    const f16* qb = qh + (size_t)bh * S * D;
    const f16* kb = kh + (size_t)bh * S * D;
    float* obase  = out + (size_t)bh * S * SP1;

    // A fragments: q rows i0 + w*16 + m, held in regs for the whole kernel
    const int arow = i0 + w * 16 + m;
    f16x8 a0 = *(const f16x8*)(qb + (size_t)arow * D + quad * 8);
    f16x8 a1 = *(const f16x8*)(qb + (size_t)arow * D + 32 + quad * 8);

    const int rbase = w * 16 + quad * 4;  // first row-in-band this lane accumulates
    const int ib    = i0 + rbase;

    // ---- Pass 1: row sums over the causal (lower) region -------------------
    float rowsum[4] = {0.f, 0.f, 0.f, 0.f};
    for (int jt = 0; jt <= it; jt++) {
        const int j0 = jt * TILE;
        const bool diag = (jt == it);
        #pragma unroll
        for (int st = 0; st < 4; st++) {
            const int j = j0 + st * 16 + m;
            f16x8 b0 = *(const f16x8*)(kb + (size_t)j * D + quad * 8);
            f16x8 b1 = *(const f16x8*)(kb + (size_t)j * D + 32 + quad * 8);
            f32x4 acc = {0.f, 0.f, 0.f, 0.f};
            acc = __builtin_amdgcn_mfma_f32_16x16x32_f16(a0, b0, acc, 0, 0, 0);
            acc = __builtin_amdgcn_mfma_f32_16x16x32_f16(a1, b1, acc, 0, 0, 0);
            #pragma unroll
            for (int r = 0; r < 4; r++) {
                float e = __expf(acc[r]);
                if (diag && j > ib + r) e = 0.f;  // upper triangle via closed form
                rowsum[r] += e;
            }
        }
    }
    // reduce across the 16 column-lanes of each quad (all quad lanes end with full sum)
    #pragma unroll
    for (int off = 1; off < 16; off <<= 1)
        #pragma unroll
        for (int r = 0; r < 4; r++) rowsum[r] += __shfl_xor(rowsum[r], off);

    float il[4], se[4];
    #pragma unroll
    for (int r = 0; r < 4; r++) {
        int i = ib + r;
        se[r] = __expf(sinks[bh * S + i]);
        il[r] = 1.0f / (rowsum[r] + (float)(S - 1 - i) + se[r]);
    }

    // ---- Pass 2: recompute lower tiles, wave-local LDS transpose, coalesced stores
    for (int jt = 0; jt <= it; jt++) {
        const int j0 = jt * TILE;
        const bool diag = (jt == it);
        #pragma unroll
        for (int st = 0; st < 4; st++) {
            const int j = j0 + st * 16 + m;
            f16x8 b0 = *(const f16x8*)(kb + (size_t)j * D + quad * 8);
            f16x8 b1 = *(const f16x8*)(kb + (size_t)j * D + 32 + quad * 8);
            f32x4 acc = {0.f, 0.f, 0.f, 0.f};
            acc = __builtin_amdgcn_mfma_f32_16x16x32_f16(a0, b0, acc, 0, 0, 0);
            acc = __builtin_amdgcn_mfma_f32_16x16x32_f16(a1, b1, acc, 0, 0, 0);
            #pragma unroll
            for (int r = 0; r < 4; r++) {
                float v = __expf(acc[r]) * il[r];
                if (diag && j > ib + r) v = il[r];  // exp(0) * il
                os[(rbase + r) * OS_PITCH + st * 16 + m] = v;
            }
        }
        // readout: same wave wrote rows [w*16, w*16+16) -> no barrier needed
        #pragma unroll
        for (int rr = 0; rr < 16; rr++) {
            int row = w * 16 + rr;
            obase[(size_t)(i0 + row) * SP1 + j0 + lane] = os[row * OS_PITCH + lane];
        }
    }

    // ---- Pass 3: constant upper region [jb, S) per row + sink column -------
    const int jb = (it + 1) * TILE;
    #pragma unroll
    for (int rr = 0; rr < 16; rr++) {
        int row = w * 16 + rr;
        int i = i0 + row;
        float v  = __shfl(il[rr & 3], (rr >> 2) * 16);
        float sv = __shfl(se[rr & 3], (rr >> 2) * 16) * v;
        float* rowp = obase + (size_t)i * SP1;
        if (lane == 0) rowp[S] = sv;  // sink column
        if (jb < S) {
            int h = (4 - ((i + jb) & 3)) & 3;      // scalar head to reach 16B alignment
            if (lane < h) rowp[jb + lane] = v;
            int start4 = jb + h;
            int n4 = (S - start4) >> 2;
            float4 vv = make_float4(v, v, v, v);
            for (int c = lane; c < n4; c += 64)
                *(float4*)(rowp + start4 + (size_t)c * 4) = vv;
            int tail = start4 + (n4 << 2);
            if (lane < S - tail) rowp[tail + lane] = v;
        }
    }
}

// ---------------------------------------------------------------------------
extern "C" void kernel_launch(void* const* d_in, const int* in_sizes, int n_in,
                              void* d_out, int out_size, void* d_ws, size_t ws_size,
                              hipStream_t stream) {
    const float* q     = (const float*)d_in[0];
    const float* k     = (const float*)d_in[1];
    const float* sinks = (const float*)d_in[2];
    float* out = (float*)d_out;

    f16* qh = (f16*)d_ws;                       // BH*S*D halfs = 8 MB
    f16* kh = qh + (size_t)BH * S * D;          // 8 MB

    prep_kernel<<<dim3(BH * S / 4), 256, 0, stream>>>(q, k, qh, kh);
    main_kernel<<<dim3(NT, BH), 256, 0, stream>>>(qh, kh, sinks, out);
}